// Round 8
// baseline (886.522 us; speedup 1.0000x reference)
//
#include <hip/hip_runtime.h>
#include <hip/hip_cooperative_groups.h>

namespace cg = cooperative_groups;

#define BLK 256

typedef __attribute__((ext_vector_type(8))) unsigned short ushort8v;
typedef __attribute__((ext_vector_type(4))) unsigned short ushort4v;
typedef __attribute__((ext_vector_type(8))) short short8v;
typedef __attribute__((ext_vector_type(4))) float f32x4;

static __device__ __forceinline__ float bf2f(unsigned short u) {
    return __uint_as_float(((unsigned)u) << 16);
}
static __device__ __forceinline__ unsigned short f2bf(float f) {
    unsigned u = __float_as_uint(f);
    u += 0x7FFF + ((u >> 16) & 1);   // RNE
    return (unsigned short)(u >> 16);
}

// ---------------------------------------------------------------- cooperative CSR build
// phase0: zero cnt/acc/ctr -> sync -> count -> sync -> block0 scan -> sync -> fill
__global__ __launch_bounds__(BLK) void k_csr(int* __restrict__ cnt, int* __restrict__ rs,
                                             int* __restrict__ cur, int* __restrict__ csrc,
                                             float* __restrict__ cw,
                                             const int* __restrict__ src,
                                             const int* __restrict__ dst,
                                             float* __restrict__ acc, int* __restrict__ ctr,
                                             int N, int E) {
    cg::grid_group grid = cg::this_grid();
    const int t = threadIdx.x;
    const int gid = blockIdx.x * BLK + t;
    const int gsz = gridDim.x * BLK;

    for (int i = gid; i < N; i += gsz) cnt[i] = 0;
    if (gid < 8) acc[gid] = 0.f;
    if (gid == 8) *ctr = 0;
    grid.sync();

    for (int i = gid; i < E; i += gsz) atomicAdd(&cnt[dst[i]], 1);
    grid.sync();

    if (blockIdx.x == 0) {
        __shared__ int sm[BLK];
        const int chunk = (N + BLK - 1) / BLK;
        const int lo = t * chunk, hi = min(lo + chunk, N);
        int s = 0;
        for (int i = lo; i < hi; ++i) s += cnt[i];
        sm[t] = s;
        __syncthreads();
        for (int off = 1; off < BLK; off <<= 1) {
            int v = (t >= off) ? sm[t - off] : 0;
            __syncthreads();
            sm[t] += v;
            __syncthreads();
        }
        int run = sm[t] - s;
        for (int i = lo; i < hi; ++i) {
            int c = cnt[i];
            rs[i] = run; cur[i] = run;
            run += c;
        }
    }
    grid.sync();

    for (int e = gid; e < E; e += gsz) {
        int d = dst[e], s = src[e];
        int p = atomicAdd(&cur[d], 1);
        csrc[p] = s;
        cw[p] = rsqrtf((1.0f + (float)cnt[s]) * (1.0f + (float)cnt[d]));
    }
}

// ---------------- fallback (non-cooperative) CSR build ----------------
__global__ void k_zero(int* __restrict__ cnt, float* __restrict__ acc,
                       int* __restrict__ ctr, int N) {
    int i = blockIdx.x * BLK + threadIdx.x;
    if (i < N) cnt[i] = 0;
    if (i < 8) acc[i] = 0.f;
    if (i == 8) *ctr = 0;
}
__global__ void k_count(const int* __restrict__ dst, int* __restrict__ cnt, int E) {
    int i = blockIdx.x * BLK + threadIdx.x;
    if (i < E) atomicAdd(&cnt[dst[i]], 1);
}
__global__ __launch_bounds__(1024) void k_scan_all(const int* __restrict__ cnt,
                                                   int* __restrict__ rs,
                                                   int* __restrict__ cur, int N) {
    __shared__ int sm[1024];
    const int t = threadIdx.x;
    const int chunk = (N + 1023) >> 10;
    const int lo = t * chunk, hi = min(lo + chunk, N);
    int s = 0;
    for (int i = lo; i < hi; ++i) s += cnt[i];
    sm[t] = s;
    __syncthreads();
    for (int off = 1; off < 1024; off <<= 1) {
        int v = (t >= off) ? sm[t - off] : 0;
        __syncthreads();
        sm[t] += v;
        __syncthreads();
    }
    int run = sm[t] - s;
    for (int i = lo; i < hi; ++i) {
        int c = cnt[i];
        rs[i] = run; cur[i] = run;
        run += c;
    }
}
__global__ void k_fill(const int* __restrict__ src, const int* __restrict__ dst,
                       const int* __restrict__ cnt, int* __restrict__ cur,
                       int* __restrict__ csrc, float* __restrict__ cw, int E) {
    int e = blockIdx.x * BLK + threadIdx.x;
    if (e >= E) return;
    int d = dst[e], s = src[e];
    int p = atomicAdd(&cur[d], 1);
    csrc[p] = s;
    cw[p] = rsqrtf((1.0f + (float)cnt[s]) * (1.0f + (float)cnt[d]));
}

// ---------------------------------------------------------------- MFMA GEMM (layer 1)
// hw1[M][64](bf16) = bf16(x) @ bf16(W1); W1 f32 [K][64] converted+transposed in staging.
template <int K>
__global__ __launch_bounds__(BLK) void k_gemm_mfma(const float* __restrict__ A,
                                                   const float* __restrict__ W,
                                                   unsigned short* __restrict__ C,
                                                   int M, int N, int B) {
    constexpr int LDA = K + 8;
    __shared__ unsigned short As[128 * LDA];
    __shared__ unsigned short Bs[64 * LDA];
    const int t = threadIdx.x;
    const int row0 = blockIdx.x * 128;

    // stage W[k][c] f32 -> Bs[c][k] bf16 (transpose)
    for (int i = t; i < 64 * K; i += BLK) {
        int k = i >> 6, c = i & 63;
        Bs[c * LDA + k] = f2bf(W[i]);
    }
    for (int i = t; i < 128 * (K / 4); i += BLK) {
        int r = i / (K / 4), c = i % (K / 4);
        int gr = row0 + r;
        float4 v = make_float4(0.f, 0.f, 0.f, 0.f);
        if (gr < M) {
            size_t ra = (size_t)(gr % B) * N + (gr / B);   // x batch-major -> node-major
            v = *reinterpret_cast<const float4*>(A + ra * K + c * 4);
        }
        ushort4v o;
        o[0] = f2bf(v.x); o[1] = f2bf(v.y); o[2] = f2bf(v.z); o[3] = f2bf(v.w);
        *reinterpret_cast<ushort4v*>(&As[r * LDA + c * 4]) = o;
    }
    __syncthreads();

    const int w = t >> 6, lane = t & 63;
    const int lrow = lane & 15;
    const int lk = (lane >> 4) * 8;

    f32x4 acc[2][4] = {};
    #pragma unroll
    for (int ks = 0; ks < K / 32; ++ks) {
        short8v a[2], b[4];
        #pragma unroll
        for (int fr = 0; fr < 2; ++fr)
            a[fr] = *reinterpret_cast<const short8v*>(
                &As[(w * 32 + fr * 16 + lrow) * LDA + ks * 32 + lk]);
        #pragma unroll
        for (int fc = 0; fc < 4; ++fc)
            b[fc] = *reinterpret_cast<const short8v*>(
                &Bs[(fc * 16 + lrow) * LDA + ks * 32 + lk]);
        #pragma unroll
        for (int fr = 0; fr < 2; ++fr)
            #pragma unroll
            for (int fc = 0; fc < 4; ++fc)
                acc[fr][fc] = __builtin_amdgcn_mfma_f32_16x16x32_bf16(
                    a[fr], b[fc], acc[fr][fc], 0, 0, 0);
    }

    __syncthreads();
    #pragma unroll
    for (int fr = 0; fr < 2; ++fr)
        #pragma unroll
        for (int fc = 0; fc < 4; ++fc)
            #pragma unroll
            for (int j = 0; j < 4; ++j)
                As[(w * 32 + fr * 16 + (lane >> 4) * 4 + j) * 72 + fc * 16 + lrow] =
                    f2bf(acc[fr][fc][j]);
    __syncthreads();
    for (int i = t; i < 128 * 8; i += BLK) {
        int r = i >> 3, c = i & 7;
        int gr = row0 + r;
        if (gr < M)
            *reinterpret_cast<ushort8v*>(C + (size_t)gr * 64 + c * 8) =
                *reinterpret_cast<const ushort8v*>(&As[r * 72 + c * 8]);
    }
}

// ---------------------------------------------------------------- edge accumulate
#define EDGE_ACC(P)                                                                 \
    {                                                                               \
        int _s = csrc[P];                                                           \
        float _w = cw[P];                                                           \
        ushort8v _x = *reinterpret_cast<const ushort8v*>(                           \
            hw + (size_t)_s * 512 + lane * 8);                                      \
        _Pragma("unroll")                                                           \
        for (int j = 0; j < 8; ++j) a[j] = fmaf(_w, bf2f(_x[j]), a[j]);             \
    }

// gather core: 2 waves per node (even/odd edges), wave h==0 carries self+bias.
#define GATHER_CORE(NODE)                                                           \
    float a[8];                                                                     \
    {                                                                               \
        const int beg = rs[NODE];                                                   \
        const int deg = cnt[NODE];                                                  \
        if (h == 0) {                                                               \
            const float self = 1.0f / (1.0f + (float)deg);                          \
            const float* bp = bias + (lane & 7) * 8;                                \
            ushort8v v = *reinterpret_cast<const ushort8v*>(                        \
                hw + (size_t)(NODE) * 512 + lane * 8);                              \
            _Pragma("unroll")                                                       \
            for (int j = 0; j < 8; ++j) a[j] = fmaf(bf2f(v[j]), self, bp[j]);       \
        } else {                                                                    \
            _Pragma("unroll")                                                       \
            for (int j = 0; j < 8; ++j) a[j] = 0.f;                                 \
        }                                                                           \
        int i = beg + h;                                                            \
        const int end = beg + deg;                                                  \
        for (; i + 6 < end; i += 8) {                                               \
            EDGE_ACC(i); EDGE_ACC(i + 2); EDGE_ACC(i + 4); EDGE_ACC(i + 6);         \
        }                                                                           \
        for (; i < end; i += 2) EDGE_ACC(i);                                        \
    }

// ---------------------------------------------------------------- fused gather1 + GEMM2
// Block = 2 dst nodes x 2 waves. agg1 combined in LDS (f32), relu->bf16 tile
// [16 rows=(node,b)][64 h], tile @ W2 (staged+transposed from f32) -> hw2 bf16.
__global__ __launch_bounds__(BLK) void k_gather_gemm(const unsigned short* __restrict__ hw,
                                                     const int* __restrict__ rs,
                                                     const int* __restrict__ cnt,
                                                     const int* __restrict__ csrc,
                                                     const float* __restrict__ cw,
                                                     const float* __restrict__ bias,
                                                     const float* __restrict__ W2,
                                                     unsigned short* __restrict__ hw2,
                                                     int N) {
    __shared__ unsigned short Ws[64 * 72];
    __shared__ unsigned short Tile[16 * 72];
    __shared__ float comb[2][512];
    const int t = threadIdx.x;
    const int wv = t >> 6, lane = t & 63;
    const int s = wv >> 1, h = wv & 1;
    const int n = blockIdx.x * 2 + s;

    // stage W2[k][c] f32 -> Ws[c][k] bf16
    for (int i = t; i < 64 * 64; i += BLK) {
        int k = i >> 6, c = i & 63;
        Ws[c * 72 + k] = f2bf(W2[i]);
    }

    GATHER_CORE(n);

    if (h == 1) {
        #pragma unroll
        for (int j = 0; j < 8; ++j) comb[s][j * 64 + lane] = a[j];
    }
    __syncthreads();
    if (h == 0) {
        ushort8v o;
        #pragma unroll
        for (int j = 0; j < 8; ++j) o[j] = f2bf(fmaxf(a[j] + comb[s][j * 64 + lane], 0.f));
        *reinterpret_cast<ushort8v*>(&Tile[(s * 8 + (lane >> 3)) * 72 + (lane & 7) * 8]) = o;
    }
    __syncthreads();

    // MFMA: wave wv -> cols wv*16..+15, rows 0..15
    const int lrow = lane & 15, lk = (lane >> 4) * 8;
    f32x4 acc = {};
    #pragma unroll
    for (int ks = 0; ks < 2; ++ks) {
        short8v af = *reinterpret_cast<const short8v*>(&Tile[lrow * 72 + ks * 32 + lk]);
        short8v bf_ = *reinterpret_cast<const short8v*>(
            &Ws[(wv * 16 + lrow) * 72 + ks * 32 + lk]);
        acc = __builtin_amdgcn_mfma_f32_16x16x32_bf16(af, bf_, acc, 0, 0, 0);
    }
    __syncthreads();
    #pragma unroll
    for (int j = 0; j < 4; ++j)
        Tile[((lane >> 4) * 4 + j) * 72 + wv * 16 + lrow] = f2bf(acc[j]);
    __syncthreads();
    if (t < 128) {
        int r = t >> 3, c = t & 7;
        *reinterpret_cast<ushort8v*>(
            hw2 + (size_t)(blockIdx.x * 2 + (r >> 3)) * 512 + (r & 7) * 64 + c * 8) =
            *reinterpret_cast<const ushort8v*>(&Tile[r * 72 + c * 8]);
    }
}

// ---------------------------------------------------------------- final gather + pool + FC
// 2 nodes x 2 waves; combine in LDS; relu+dot fcw; 8 atomics/block; last block -> out.
__global__ __launch_bounds__(BLK) void k_gather_final(const unsigned short* __restrict__ hw,
                                                      const int* __restrict__ rs,
                                                      const int* __restrict__ cnt,
                                                      const int* __restrict__ csrc,
                                                      const float* __restrict__ cw,
                                                      const float* __restrict__ bias,
                                                      const float* __restrict__ fcw,
                                                      const float* __restrict__ addf,
                                                      const float* __restrict__ fcb,
                                                      float* __restrict__ acc, int* __restrict__ ctr,
                                                      float* __restrict__ out,
                                                      int N, int H, int nblk) {
    __shared__ float comb[2][512];
    __shared__ float sm[2][8];
    __shared__ int lastFlag;
    const int t = threadIdx.x;
    const int wv = t >> 6, lane = t & 63;
    const int s = wv >> 1, h = wv & 1;
    const int n = blockIdx.x * 2 + s;

    GATHER_CORE(n);

    if (h == 1) {
        #pragma unroll
        for (int j = 0; j < 8; ++j) comb[s][j * 64 + lane] = a[j];
    }
    __syncthreads();
    if (h == 0) {
        const float* fp = fcw + (lane & 7) * 8;
        float sd = 0.f;
        #pragma unroll
        for (int j = 0; j < 8; ++j)
            sd = fmaf(fmaxf(a[j] + comb[s][j * 64 + lane], 0.f), fp[j], sd);
        sd += __shfl_xor(sd, 1, 64);
        sd += __shfl_xor(sd, 2, 64);
        sd += __shfl_xor(sd, 4, 64);
        if ((lane & 7) == 0) sm[s][lane >> 3] = sd;
    }
    __syncthreads();
    if (t < 8) {
        atomicAdd(&acc[t], sm[0][t] + sm[1][t]);
        __threadfence();
    }
    __syncthreads();
    if (t == 0) {
        int old = atomicAdd(ctr, 1);
        lastFlag = (old == nblk - 1) ? 1 : 0;
    }
    __syncthreads();
    if (lastFlag && t < 8) {
        float v = atomicAdd(&acc[t], 0.f);   // read fully-accumulated value
        out[t] = v / (float)N + addf[t] * fcw[H] + fcb[0];
    }
}

// ---------------------------------------------------------------- launch
extern "C" void kernel_launch(void* const* d_in, const int* in_sizes, int n_in,
                              void* d_out, int out_size, void* d_ws, size_t ws_size,
                              hipStream_t stream) {
    const float* x    = (const float*)d_in[0];
    const float* addf = (const float*)d_in[1];
    const int*   ei   = (const int*)d_in[2];
    const float* W1   = (const float*)d_in[3];
    const float* b1   = (const float*)d_in[4];
    const float* W2   = (const float*)d_in[5];
    const float* b2   = (const float*)d_in[6];
    const float* fcw  = (const float*)d_in[7];
    const float* fcb  = (const float*)d_in[8];
    float* out = (float*)d_out;

    const int B  = in_sizes[1];            // 8
    const int H  = in_sizes[4];            // 64
    const int IN = in_sizes[3] / H;        // 128
    const int E  = in_sizes[2] / 2;        // 320000
    const int N  = in_sizes[0] / (B * IN); // 20000
    const int* srcp = ei;
    const int* dstp = ei + E;

    const int M = B * N;                   // 160000 node-major rows

    size_t bufsz = (size_t)M * H;
    unsigned short* bufA = (unsigned short*)d_ws;      // hw1 [N][512] bf16
    unsigned short* bufB = bufA + bufsz;               // hw2 [N][512] bf16
    int*   cnt  = (int*)(bufB + bufsz);
    int*   rs   = cnt + N;
    int*   cur  = rs + N;
    int*   csrc = cur + N;
    float* cw   = (float*)(csrc + E);
    float* acc  = (float*)(cw + E);
    int*   ctr  = (int*)(acc + 8);

    const int nbN = (N + BLK - 1) / BLK;
    const int nbE = (E + BLK - 1) / BLK;
    const int nodes2 = N / 2;              // gather blocks (2 nodes/block)

    // --- CSR build: cooperative single launch, fallback to 4 launches ---
    {
        void* args[] = {(void*)&cnt, (void*)&rs, (void*)&cur, (void*)&csrc, (void*)&cw,
                        (void*)&srcp, (void*)&dstp, (void*)&acc, (void*)&ctr,
                        (void*)&N, (void*)&E};
        hipError_t err = hipLaunchCooperativeKernel((const void*)k_csr, dim3(1024),
                                                    dim3(BLK), args, 0, stream);
        if (err != hipSuccess) {
            (void)hipGetLastError();       // clear
            k_zero<<<dim3(nbN), dim3(BLK), 0, stream>>>(cnt, acc, ctr, N);
            k_count<<<dim3(nbE), dim3(BLK), 0, stream>>>(dstp, cnt, E);
            k_scan_all<<<dim3(1), dim3(1024), 0, stream>>>(cnt, rs, cur, N);
            k_fill<<<dim3(nbE), dim3(BLK), 0, stream>>>(srcp, dstp, cnt, cur, csrc, cw, E);
        }
    }

    // layer 1: hw1 = bf16(x) @ bf16(W1) -> bufA (node-major)
    k_gemm_mfma<128><<<dim3((M + 127) / 128), dim3(BLK), 0, stream>>>(
        x, W1, bufA, M, N, B);

    // fused: agg1 = gather(hw1)+self+b1; hw2 = relu(agg1) @ W2 -> bufB
    k_gather_gemm<<<dim3(nodes2), dim3(BLK), 0, stream>>>(
        bufA, rs, cnt, csrc, cw, b1, W2, bufB, N);

    // fused final: gather(hw2)+self+b2, relu, mean-pool, FC -> out (last block)
    k_gather_final<<<dim3(nodes2), dim3(BLK), 0, stream>>>(
        bufB, rs, cnt, csrc, cw, b2, fcw, addf, fcb, acc, ctr, out, N, H, nodes2);
}

// Round 9
// 592.186 us; speedup vs baseline: 1.4970x; 1.4970x over previous
//
#include <hip/hip_runtime.h>
#include <hip/hip_cooperative_groups.h>

namespace cg = cooperative_groups;

#define BLK 256

typedef __attribute__((ext_vector_type(8))) unsigned short ushort8v;
typedef __attribute__((ext_vector_type(4))) unsigned short ushort4v;
typedef __attribute__((ext_vector_type(8))) short short8v;
typedef __attribute__((ext_vector_type(4))) float f32x4;

static __device__ __forceinline__ float bf2f(unsigned short u) {
    return __uint_as_float(((unsigned)u) << 16);
}
static __device__ __forceinline__ unsigned short f2bf(float f) {
    unsigned u = __float_as_uint(f);
    u += 0x7FFF + ((u >> 16) & 1);   // RNE
    return (unsigned short)(u >> 16);
}

// ---------------------------------------------------------------- cooperative CSR build
__global__ __launch_bounds__(BLK) void k_csr(int* __restrict__ cnt, int* __restrict__ rs,
                                             int* __restrict__ cur, int* __restrict__ csrc,
                                             float* __restrict__ cw,
                                             const int* __restrict__ src,
                                             const int* __restrict__ dst,
                                             int N, int E) {
    cg::grid_group grid = cg::this_grid();
    const int t = threadIdx.x;
    const int gid = blockIdx.x * BLK + t;
    const int gsz = gridDim.x * BLK;

    for (int i = gid; i < N; i += gsz) cnt[i] = 0;
    grid.sync();

    for (int i = gid; i < E; i += gsz) atomicAdd(&cnt[dst[i]], 1);
    grid.sync();

    if (blockIdx.x == 0) {
        __shared__ int sm[BLK];
        const int chunk = (N + BLK - 1) / BLK;
        const int lo = t * chunk, hi = min(lo + chunk, N);
        int s = 0;
        for (int i = lo; i < hi; ++i) s += cnt[i];
        sm[t] = s;
        __syncthreads();
        for (int off = 1; off < BLK; off <<= 1) {
            int v = (t >= off) ? sm[t - off] : 0;
            __syncthreads();
            sm[t] += v;
            __syncthreads();
        }
        int run = sm[t] - s;
        for (int i = lo; i < hi; ++i) {
            int c = cnt[i];
            rs[i] = run; cur[i] = run;
            run += c;
        }
    }
    grid.sync();

    for (int e = gid; e < E; e += gsz) {
        int d = dst[e], s = src[e];
        int p = atomicAdd(&cur[d], 1);
        csrc[p] = s;
        cw[p] = rsqrtf((1.0f + (float)cnt[s]) * (1.0f + (float)cnt[d]));
    }
}

// ---------------- fallback (non-cooperative) CSR build ----------------
__global__ void k_zero(int* __restrict__ cnt, int N) {
    int i = blockIdx.x * BLK + threadIdx.x;
    if (i < N) cnt[i] = 0;
}
__global__ void k_count(const int* __restrict__ dst, int* __restrict__ cnt, int E) {
    int i = blockIdx.x * BLK + threadIdx.x;
    if (i < E) atomicAdd(&cnt[dst[i]], 1);
}
__global__ __launch_bounds__(1024) void k_scan_all(const int* __restrict__ cnt,
                                                   int* __restrict__ rs,
                                                   int* __restrict__ cur, int N) {
    __shared__ int sm[1024];
    const int t = threadIdx.x;
    const int chunk = (N + 1023) >> 10;
    const int lo = t * chunk, hi = min(lo + chunk, N);
    int s = 0;
    for (int i = lo; i < hi; ++i) s += cnt[i];
    sm[t] = s;
    __syncthreads();
    for (int off = 1; off < 1024; off <<= 1) {
        int v = (t >= off) ? sm[t - off] : 0;
        __syncthreads();
        sm[t] += v;
        __syncthreads();
    }
    int run = sm[t] - s;
    for (int i = lo; i < hi; ++i) {
        int c = cnt[i];
        rs[i] = run; cur[i] = run;
        run += c;
    }
}
__global__ void k_fill(const int* __restrict__ src, const int* __restrict__ dst,
                       const int* __restrict__ cnt, int* __restrict__ cur,
                       int* __restrict__ csrc, float* __restrict__ cw, int E) {
    int e = blockIdx.x * BLK + threadIdx.x;
    if (e >= E) return;
    int d = dst[e], s = src[e];
    int p = atomicAdd(&cur[d], 1);
    csrc[p] = s;
    cw[p] = rsqrtf((1.0f + (float)cnt[s]) * (1.0f + (float)cnt[d]));
}

// ---------------------------------------------------------------- MFMA GEMM (layer 1)
template <int K>
__global__ __launch_bounds__(BLK) void k_gemm_mfma(const float* __restrict__ A,
                                                   const float* __restrict__ W,
                                                   unsigned short* __restrict__ C,
                                                   int M, int N, int B) {
    constexpr int LDA = K + 8;
    __shared__ unsigned short As[128 * LDA];
    __shared__ unsigned short Bs[64 * LDA];
    const int t = threadIdx.x;
    const int row0 = blockIdx.x * 128;

    // stage W[k][c] f32 -> Bs[c][k] bf16 (transpose)
    for (int i = t; i < 64 * K; i += BLK) {
        int k = i >> 6, c = i & 63;
        Bs[c * LDA + k] = f2bf(W[i]);
    }
    for (int i = t; i < 128 * (K / 4); i += BLK) {
        int r = i / (K / 4), c = i % (K / 4);
        int gr = row0 + r;
        float4 v = make_float4(0.f, 0.f, 0.f, 0.f);
        if (gr < M) {
            size_t ra = (size_t)(gr % B) * N + (gr / B);   // x batch-major -> node-major
            v = *reinterpret_cast<const float4*>(A + ra * K + c * 4);
        }
        ushort4v o;
        o[0] = f2bf(v.x); o[1] = f2bf(v.y); o[2] = f2bf(v.z); o[3] = f2bf(v.w);
        *reinterpret_cast<ushort4v*>(&As[r * LDA + c * 4]) = o;
    }
    __syncthreads();

    const int w = t >> 6, lane = t & 63;
    const int lrow = lane & 15;
    const int lk = (lane >> 4) * 8;

    f32x4 acc[2][4] = {};
    #pragma unroll
    for (int ks = 0; ks < K / 32; ++ks) {
        short8v a[2], b[4];
        #pragma unroll
        for (int fr = 0; fr < 2; ++fr)
            a[fr] = *reinterpret_cast<const short8v*>(
                &As[(w * 32 + fr * 16 + lrow) * LDA + ks * 32 + lk]);
        #pragma unroll
        for (int fc = 0; fc < 4; ++fc)
            b[fc] = *reinterpret_cast<const short8v*>(
                &Bs[(fc * 16 + lrow) * LDA + ks * 32 + lk]);
        #pragma unroll
        for (int fr = 0; fr < 2; ++fr)
            #pragma unroll
            for (int fc = 0; fc < 4; ++fc)
                acc[fr][fc] = __builtin_amdgcn_mfma_f32_16x16x32_bf16(
                    a[fr], b[fc], acc[fr][fc], 0, 0, 0);
    }

    __syncthreads();
    #pragma unroll
    for (int fr = 0; fr < 2; ++fr)
        #pragma unroll
        for (int fc = 0; fc < 4; ++fc)
            #pragma unroll
            for (int j = 0; j < 4; ++j)
                As[(w * 32 + fr * 16 + (lane >> 4) * 4 + j) * 72 + fc * 16 + lrow] =
                    f2bf(acc[fr][fc][j]);
    __syncthreads();
    for (int i = t; i < 128 * 8; i += BLK) {
        int r = i >> 3, c = i & 7;
        int gr = row0 + r;
        if (gr < M)
            *reinterpret_cast<ushort8v*>(C + (size_t)gr * 64 + c * 8) =
                *reinterpret_cast<const ushort8v*>(&As[r * 72 + c * 8]);
    }
}

// ---------------------------------------------------------------- edge accumulate
#define EDGE_ACC(P)                                                                 \
    {                                                                               \
        int _s = csrc[P];                                                           \
        float _w = cw[P];                                                           \
        ushort8v _x = *reinterpret_cast<const ushort8v*>(                           \
            hw + (size_t)_s * 512 + lane * 8);                                      \
        _Pragma("unroll")                                                           \
        for (int j = 0; j < 8; ++j) a[j] = fmaf(_w, bf2f(_x[j]), a[j]);             \
    }

// gather core: 2 waves per node (even/odd edges), wave h==0 carries self+bias.
#define GATHER_CORE(NODE)                                                           \
    float a[8];                                                                     \
    {                                                                               \
        const int beg = rs[NODE];                                                   \
        const int deg = cnt[NODE];                                                  \
        if (h == 0) {                                                               \
            const float self = 1.0f / (1.0f + (float)deg);                          \
            const float* bp = bias + (lane & 7) * 8;                                \
            ushort8v v = *reinterpret_cast<const ushort8v*>(                        \
                hw + (size_t)(NODE) * 512 + lane * 8);                              \
            _Pragma("unroll")                                                       \
            for (int j = 0; j < 8; ++j) a[j] = fmaf(bf2f(v[j]), self, bp[j]);       \
        } else {                                                                    \
            _Pragma("unroll")                                                       \
            for (int j = 0; j < 8; ++j) a[j] = 0.f;                                 \
        }                                                                           \
        int i = beg + h;                                                            \
        const int end = beg + deg;                                                  \
        for (; i + 6 < end; i += 8) {                                               \
            EDGE_ACC(i); EDGE_ACC(i + 2); EDGE_ACC(i + 4); EDGE_ACC(i + 6);         \
        }                                                                           \
        for (; i < end; i += 2) EDGE_ACC(i);                                        \
    }

// ---------------------------------------------------------------- fused gather1 + GEMM2
__global__ __launch_bounds__(BLK) void k_gather_gemm(const unsigned short* __restrict__ hw,
                                                     const int* __restrict__ rs,
                                                     const int* __restrict__ cnt,
                                                     const int* __restrict__ csrc,
                                                     const float* __restrict__ cw,
                                                     const float* __restrict__ bias,
                                                     const float* __restrict__ W2,
                                                     unsigned short* __restrict__ hw2,
                                                     int N) {
    __shared__ unsigned short Ws[64 * 72];
    __shared__ unsigned short Tile[16 * 72];
    __shared__ float comb[2][512];
    const int t = threadIdx.x;
    const int wv = t >> 6, lane = t & 63;
    const int s = wv >> 1, h = wv & 1;
    const int n = blockIdx.x * 2 + s;

    // stage W2[k][c] f32 -> Ws[c][k] bf16
    for (int i = t; i < 64 * 64; i += BLK) {
        int k = i >> 6, c = i & 63;
        Ws[c * 72 + k] = f2bf(W2[i]);
    }

    GATHER_CORE(n);

    if (h == 1) {
        #pragma unroll
        for (int j = 0; j < 8; ++j) comb[s][j * 64 + lane] = a[j];
    }
    __syncthreads();
    if (h == 0) {
        ushort8v o;
        #pragma unroll
        for (int j = 0; j < 8; ++j) o[j] = f2bf(fmaxf(a[j] + comb[s][j * 64 + lane], 0.f));
        *reinterpret_cast<ushort8v*>(&Tile[(s * 8 + (lane >> 3)) * 72 + (lane & 7) * 8]) = o;
    }
    __syncthreads();

    // MFMA: wave wv -> cols wv*16..+15, rows 0..15
    const int lrow = lane & 15, lk = (lane >> 4) * 8;
    f32x4 acc = {};
    #pragma unroll
    for (int ks = 0; ks < 2; ++ks) {
        short8v af = *reinterpret_cast<const short8v*>(&Tile[lrow * 72 + ks * 32 + lk]);
        short8v bf_ = *reinterpret_cast<const short8v*>(
            &Ws[(wv * 16 + lrow) * 72 + ks * 32 + lk]);
        acc = __builtin_amdgcn_mfma_f32_16x16x32_bf16(af, bf_, acc, 0, 0, 0);
    }
    __syncthreads();
    #pragma unroll
    for (int j = 0; j < 4; ++j)
        Tile[((lane >> 4) * 4 + j) * 72 + wv * 16 + lrow] = f2bf(acc[j]);
    __syncthreads();
    if (t < 128) {
        int r = t >> 3, c = t & 7;
        *reinterpret_cast<ushort8v*>(
            hw2 + (size_t)(blockIdx.x * 2 + (r >> 3)) * 512 + (r & 7) * 64 + c * 8) =
            *reinterpret_cast<const ushort8v*>(&Tile[r * 72 + c * 8]);
    }
}

// ---------------------------------------------------------------- final gather + pool + FC
// 2 nodes x 2 waves; combine in LDS; relu + dot fcw; per-block partials (no atomics).
__global__ __launch_bounds__(BLK) void k_gather_final(const unsigned short* __restrict__ hw,
                                                      const int* __restrict__ rs,
                                                      const int* __restrict__ cnt,
                                                      const int* __restrict__ csrc,
                                                      const float* __restrict__ cw,
                                                      const float* __restrict__ bias,
                                                      const float* __restrict__ fcw,
                                                      float* __restrict__ partial, int N) {
    __shared__ float comb[2][512];
    __shared__ float sm[2][8];
    const int t = threadIdx.x;
    const int wv = t >> 6, lane = t & 63;
    const int s = wv >> 1, h = wv & 1;
    const int n = blockIdx.x * 2 + s;

    GATHER_CORE(n);

    if (h == 1) {
        #pragma unroll
        for (int j = 0; j < 8; ++j) comb[s][j * 64 + lane] = a[j];
    }
    __syncthreads();
    if (h == 0) {
        const float* fp = fcw + (lane & 7) * 8;
        float sd = 0.f;
        #pragma unroll
        for (int j = 0; j < 8; ++j)
            sd = fmaf(fmaxf(a[j] + comb[s][j * 64 + lane], 0.f), fp[j], sd);
        sd += __shfl_xor(sd, 1, 64);
        sd += __shfl_xor(sd, 2, 64);
        sd += __shfl_xor(sd, 4, 64);
        if ((lane & 7) == 0) sm[s][lane >> 3] = sd;
    }
    __syncthreads();
    if (t < 8)
        partial[(size_t)blockIdx.x * 8 + t] = sm[0][t] + sm[1][t];
}

// ---------------------------------------------------------------- finish
__global__ void k_finish(const float* __restrict__ partial, int nblk,
                         const float* __restrict__ addf, const float* __restrict__ fcw,
                         const float* __restrict__ fcb, float* __restrict__ out,
                         int N, int H) {
    int b = blockIdx.x;
    float s = 0.f;
    for (int i = threadIdx.x; i < nblk; i += BLK) s += partial[(size_t)i * 8 + b];
    __shared__ float sm[BLK / 64];
    int lane = threadIdx.x & 63, w = threadIdx.x >> 6;
    #pragma unroll
    for (int off = 32; off; off >>= 1) s += __shfl_down(s, off, 64);
    if (lane == 0) sm[w] = s;
    __syncthreads();
    if (threadIdx.x == 0) {
        float t = sm[0] + sm[1] + sm[2] + sm[3];
        out[b] = t / (float)N + addf[b] * fcw[H] + fcb[0];
    }
}

// ---------------------------------------------------------------- launch
extern "C" void kernel_launch(void* const* d_in, const int* in_sizes, int n_in,
                              void* d_out, int out_size, void* d_ws, size_t ws_size,
                              hipStream_t stream) {
    const float* x    = (const float*)d_in[0];
    const float* addf = (const float*)d_in[1];
    const int*   ei   = (const int*)d_in[2];
    const float* W1   = (const float*)d_in[3];
    const float* b1   = (const float*)d_in[4];
    const float* W2   = (const float*)d_in[5];
    const float* b2   = (const float*)d_in[6];
    const float* fcw  = (const float*)d_in[7];
    const float* fcb  = (const float*)d_in[8];
    float* out = (float*)d_out;

    const int B  = in_sizes[1];            // 8
    const int H  = in_sizes[4];            // 64
    const int IN = in_sizes[3] / H;        // 128
    const int E  = in_sizes[2] / 2;        // 320000
    const int N  = in_sizes[0] / (B * IN); // 20000
    const int* srcp = ei;
    const int* dstp = ei + E;

    const int M = B * N;                   // 160000 node-major rows

    size_t bufsz = (size_t)M * H;
    unsigned short* bufA = (unsigned short*)d_ws;      // hw1 [N][512] bf16
    unsigned short* bufB = bufA + bufsz;               // hw2 [N][512] bf16
    int*   cnt  = (int*)(bufB + bufsz);
    int*   rs   = cnt + N;
    int*   cur  = rs + N;
    int*   csrc = cur + N;
    float* cw   = (float*)(csrc + E);
    float* partial = (float*)(cw + E);

    const int nbN = (N + BLK - 1) / BLK;
    const int nbE = (E + BLK - 1) / BLK;
    const int nodes2 = N / 2;              // gather blocks (2 nodes/block)

    // --- CSR build: cooperative single launch, fallback to 4 launches ---
    {
        void* args[] = {(void*)&cnt, (void*)&rs, (void*)&cur, (void*)&csrc, (void*)&cw,
                        (void*)&srcp, (void*)&dstp, (void*)&N, (void*)&E};
        hipError_t err = hipLaunchCooperativeKernel((const void*)k_csr, dim3(1024),
                                                    dim3(BLK), args, 0, stream);
        if (err != hipSuccess) {
            (void)hipGetLastError();       // clear
            k_zero<<<dim3(nbN), dim3(BLK), 0, stream>>>(cnt, N);
            k_count<<<dim3(nbE), dim3(BLK), 0, stream>>>(dstp, cnt, E);
            k_scan_all<<<dim3(1), dim3(1024), 0, stream>>>(cnt, rs, cur, N);
            k_fill<<<dim3(nbE), dim3(BLK), 0, stream>>>(srcp, dstp, cnt, cur, csrc, cw, E);
        }
    }

    // layer 1: hw1 = bf16(x) @ bf16(W1) -> bufA (node-major)
    k_gemm_mfma<128><<<dim3((M + 127) / 128), dim3(BLK), 0, stream>>>(
        x, W1, bufA, M, N, B);

    // fused: agg1 = gather(hw1)+self+b1; hw2 = relu(agg1) @ W2 -> bufB
    k_gather_gemm<<<dim3(nodes2), dim3(BLK), 0, stream>>>(
        bufA, rs, cnt, csrc, cw, b1, W2, bufB, N);

    // fused final: gather(hw2)+self+b2, relu, mean-pool, FC dot -> partials
    k_gather_final<<<dim3(nodes2), dim3(BLK), 0, stream>>>(
        bufB, rs, cnt, csrc, cw, b2, fcw, partial, N);

    k_finish<<<dim3(B), dim3(BLK), 0, stream>>>(partial, nodes2, addf, fcw, fcb, out, N, H);
}

// Round 10
// 319.367 us; speedup vs baseline: 2.7759x; 1.8543x over previous
//
#include <hip/hip_runtime.h>

#define BLK 256

typedef __attribute__((ext_vector_type(8))) unsigned short ushort8v;
typedef __attribute__((ext_vector_type(4))) unsigned short ushort4v;
typedef __attribute__((ext_vector_type(8))) short short8v;
typedef __attribute__((ext_vector_type(4))) float f32x4;

static __device__ __forceinline__ float bf2f(unsigned short u) {
    return __uint_as_float(((unsigned)u) << 16);
}
static __device__ __forceinline__ unsigned short f2bf(float f) {
    unsigned u = __float_as_uint(f);
    u += 0x7FFF + ((u >> 16) & 1);   // RNE
    return (unsigned short)(u >> 16);
}

// ---------------------------------------------------------------- CSR build
__global__ void k_count(const int* __restrict__ dst, int* __restrict__ cnt, int E) {
    int i = blockIdx.x * BLK + threadIdx.x;
    if (i < E) atomicAdd(&cnt[dst[i]], 1);
}

__global__ __launch_bounds__(1024) void k_scan_all(const int* __restrict__ cnt,
                                                   int* __restrict__ rs,
                                                   int* __restrict__ cur, int N) {
    __shared__ int sm[1024];
    const int t = threadIdx.x;
    const int chunk = (N + 1023) >> 10;
    const int lo = t * chunk, hi = min(lo + chunk, N);
    int s = 0;
    for (int i = lo; i < hi; ++i) s += cnt[i];
    sm[t] = s;
    __syncthreads();
    for (int off = 1; off < 1024; off <<= 1) {
        int v = (t >= off) ? sm[t - off] : 0;
        __syncthreads();
        sm[t] += v;
        __syncthreads();
    }
    int run = sm[t] - s;
    for (int i = lo; i < hi; ++i) {
        int c = cnt[i];
        rs[i] = run; cur[i] = run;
        run += c;
    }
}

__global__ void k_fill(const int* __restrict__ src, const int* __restrict__ dst,
                       const int* __restrict__ cnt, int* __restrict__ cur,
                       int* __restrict__ csrc, float* __restrict__ cw, int E) {
    int e = blockIdx.x * BLK + threadIdx.x;
    if (e >= E) return;
    int d = dst[e], s = src[e];
    int p = atomicAdd(&cur[d], 1);
    csrc[p] = s;
    cw[p] = rsqrtf((1.0f + (float)cnt[s]) * (1.0f + (float)cnt[d]));
}

// ---------------------------------------------------------------- MFMA GEMM (layer 1)
template <int K>
__global__ __launch_bounds__(BLK) void k_gemm_mfma(const float* __restrict__ A,
                                                   const float* __restrict__ W,
                                                   unsigned short* __restrict__ C,
                                                   int M, int N, int B) {
    constexpr int LDA = K + 8;
    __shared__ unsigned short As[128 * LDA];
    __shared__ unsigned short Bs[64 * LDA];
    const int t = threadIdx.x;
    const int row0 = blockIdx.x * 128;

    // stage W[k][c] f32 -> Bs[c][k] bf16 (transpose)
    for (int i = t; i < 64 * K; i += BLK) {
        int k = i >> 6, c = i & 63;
        Bs[c * LDA + k] = f2bf(W[i]);
    }
    for (int i = t; i < 128 * (K / 4); i += BLK) {
        int r = i / (K / 4), c = i % (K / 4);
        int gr = row0 + r;
        float4 v = make_float4(0.f, 0.f, 0.f, 0.f);
        if (gr < M) {
            size_t ra = (size_t)(gr % B) * N + (gr / B);   // x batch-major -> node-major
            v = *reinterpret_cast<const float4*>(A + ra * K + c * 4);
        }
        ushort4v o;
        o[0] = f2bf(v.x); o[1] = f2bf(v.y); o[2] = f2bf(v.z); o[3] = f2bf(v.w);
        *reinterpret_cast<ushort4v*>(&As[r * LDA + c * 4]) = o;
    }
    __syncthreads();

    const int w = t >> 6, lane = t & 63;
    const int lrow = lane & 15;
    const int lk = (lane >> 4) * 8;

    f32x4 acc[2][4] = {};
    #pragma unroll
    for (int ks = 0; ks < K / 32; ++ks) {
        short8v a[2], b[4];
        #pragma unroll
        for (int fr = 0; fr < 2; ++fr)
            a[fr] = *reinterpret_cast<const short8v*>(
                &As[(w * 32 + fr * 16 + lrow) * LDA + ks * 32 + lk]);
        #pragma unroll
        for (int fc = 0; fc < 4; ++fc)
            b[fc] = *reinterpret_cast<const short8v*>(
                &Bs[(fc * 16 + lrow) * LDA + ks * 32 + lk]);
        #pragma unroll
        for (int fr = 0; fr < 2; ++fr)
            #pragma unroll
            for (int fc = 0; fc < 4; ++fc)
                acc[fr][fc] = __builtin_amdgcn_mfma_f32_16x16x32_bf16(
                    a[fr], b[fc], acc[fr][fc], 0, 0, 0);
    }

    __syncthreads();
    #pragma unroll
    for (int fr = 0; fr < 2; ++fr)
        #pragma unroll
        for (int fc = 0; fc < 4; ++fc)
            #pragma unroll
            for (int j = 0; j < 4; ++j)
                As[(w * 32 + fr * 16 + (lane >> 4) * 4 + j) * 72 + fc * 16 + lrow] =
                    f2bf(acc[fr][fc][j]);
    __syncthreads();
    for (int i = t; i < 128 * 8; i += BLK) {
        int r = i >> 3, c = i & 7;
        int gr = row0 + r;
        if (gr < M)
            *reinterpret_cast<ushort8v*>(C + (size_t)gr * 64 + c * 8) =
                *reinterpret_cast<const ushort8v*>(&As[r * 72 + c * 8]);
    }
}

// ---------------------------------------------------------------- edge accumulate
#define EDGE_ACC(P)                                                                 \
    {                                                                               \
        int _s = csrc[P];                                                           \
        float _w = cw[P];                                                           \
        ushort8v _x = *reinterpret_cast<const ushort8v*>(                           \
            hw + (size_t)_s * 512 + lane * 8);                                      \
        _Pragma("unroll")                                                           \
        for (int j = 0; j < 8; ++j) a[j] = fmaf(_w, bf2f(_x[j]), a[j]);             \
    }

// gather core: 2 waves per node (even/odd edges), wave h==0 carries self+bias.
#define GATHER_CORE(NODE)                                                           \
    float a[8];                                                                     \
    {                                                                               \
        const int beg = rs[NODE];                                                   \
        const int deg = cnt[NODE];                                                  \
        if (h == 0) {                                                               \
            const float self = 1.0f / (1.0f + (float)deg);                          \
            const float* bp = bias + (lane & 7) * 8;                                \
            ushort8v v = *reinterpret_cast<const ushort8v*>(                        \
                hw + (size_t)(NODE) * 512 + lane * 8);                              \
            _Pragma("unroll")                                                       \
            for (int j = 0; j < 8; ++j) a[j] = fmaf(bf2f(v[j]), self, bp[j]);       \
        } else {                                                                    \
            _Pragma("unroll")                                                       \
            for (int j = 0; j < 8; ++j) a[j] = 0.f;                                 \
        }                                                                           \
        int i = beg + h;                                                            \
        const int end = beg + deg;                                                  \
        for (; i + 6 < end; i += 8) {                                               \
            EDGE_ACC(i); EDGE_ACC(i + 2); EDGE_ACC(i + 4); EDGE_ACC(i + 6);         \
        }                                                                           \
        for (; i < end; i += 2) EDGE_ACC(i);                                        \
    }

// ---------------------------------------------------------------- fused gather1 + GEMM2
__global__ __launch_bounds__(BLK) void k_gather_gemm(const unsigned short* __restrict__ hw,
                                                     const int* __restrict__ rs,
                                                     const int* __restrict__ cnt,
                                                     const int* __restrict__ csrc,
                                                     const float* __restrict__ cw,
                                                     const float* __restrict__ bias,
                                                     const float* __restrict__ W2,
                                                     unsigned short* __restrict__ hw2,
                                                     int N) {
    __shared__ unsigned short Ws[64 * 72];
    __shared__ unsigned short Tile[16 * 72];
    __shared__ float comb[2][512];
    const int t = threadIdx.x;
    const int wv = t >> 6, lane = t & 63;
    const int s = wv >> 1, h = wv & 1;
    const int n = blockIdx.x * 2 + s;

    // stage W2[k][c] f32 -> Ws[c][k] bf16
    for (int i = t; i < 64 * 64; i += BLK) {
        int k = i >> 6, c = i & 63;
        Ws[c * 72 + k] = f2bf(W2[i]);
    }

    GATHER_CORE(n);

    if (h == 1) {
        #pragma unroll
        for (int j = 0; j < 8; ++j) comb[s][j * 64 + lane] = a[j];
    }
    __syncthreads();
    if (h == 0) {
        ushort8v o;
        #pragma unroll
        for (int j = 0; j < 8; ++j) o[j] = f2bf(fmaxf(a[j] + comb[s][j * 64 + lane], 0.f));
        *reinterpret_cast<ushort8v*>(&Tile[(s * 8 + (lane >> 3)) * 72 + (lane & 7) * 8]) = o;
    }
    __syncthreads();

    // MFMA: wave wv -> cols wv*16..+15, rows 0..15
    const int lrow = lane & 15, lk = (lane >> 4) * 8;
    f32x4 acc = {};
    #pragma unroll
    for (int ks = 0; ks < 2; ++ks) {
        short8v af = *reinterpret_cast<const short8v*>(&Tile[lrow * 72 + ks * 32 + lk]);
        short8v bf_ = *reinterpret_cast<const short8v*>(
            &Ws[(wv * 16 + lrow) * 72 + ks * 32 + lk]);
        acc = __builtin_amdgcn_mfma_f32_16x16x32_bf16(af, bf_, acc, 0, 0, 0);
    }
    __syncthreads();
    #pragma unroll
    for (int j = 0; j < 4; ++j)
        Tile[((lane >> 4) * 4 + j) * 72 + wv * 16 + lrow] = f2bf(acc[j]);
    __syncthreads();
    if (t < 128) {
        int r = t >> 3, c = t & 7;
        *reinterpret_cast<ushort8v*>(
            hw2 + (size_t)(blockIdx.x * 2 + (r >> 3)) * 512 + (r & 7) * 64 + c * 8) =
            *reinterpret_cast<const ushort8v*>(&Tile[r * 72 + c * 8]);
    }
}

// ---------------------------------------------------------------- final gather + pool + FC
__global__ __launch_bounds__(BLK) void k_gather_final(const unsigned short* __restrict__ hw,
                                                      const int* __restrict__ rs,
                                                      const int* __restrict__ cnt,
                                                      const int* __restrict__ csrc,
                                                      const float* __restrict__ cw,
                                                      const float* __restrict__ bias,
                                                      const float* __restrict__ fcw,
                                                      float* __restrict__ partial, int N) {
    __shared__ float comb[2][512];
    __shared__ float sm[2][8];
    const int t = threadIdx.x;
    const int wv = t >> 6, lane = t & 63;
    const int s = wv >> 1, h = wv & 1;
    const int n = blockIdx.x * 2 + s;

    GATHER_CORE(n);

    if (h == 1) {
        #pragma unroll
        for (int j = 0; j < 8; ++j) comb[s][j * 64 + lane] = a[j];
    }
    __syncthreads();
    if (h == 0) {
        const float* fp = fcw + (lane & 7) * 8;
        float sd = 0.f;
        #pragma unroll
        for (int j = 0; j < 8; ++j)
            sd = fmaf(fmaxf(a[j] + comb[s][j * 64 + lane], 0.f), fp[j], sd);
        sd += __shfl_xor(sd, 1, 64);
        sd += __shfl_xor(sd, 2, 64);
        sd += __shfl_xor(sd, 4, 64);
        if ((lane & 7) == 0) sm[s][lane >> 3] = sd;
    }
    __syncthreads();
    if (t < 8)
        partial[(size_t)blockIdx.x * 8 + t] = sm[0][t] + sm[1][t];
}

// ---------------------------------------------------------------- finish
__global__ void k_finish(const float* __restrict__ partial, int nblk,
                         const float* __restrict__ addf, const float* __restrict__ fcw,
                         const float* __restrict__ fcb, float* __restrict__ out,
                         int N, int H) {
    int b = blockIdx.x;
    float s = 0.f;
    for (int i = threadIdx.x; i < nblk; i += BLK) s += partial[(size_t)i * 8 + b];
    __shared__ float sm[BLK / 64];
    int lane = threadIdx.x & 63, w = threadIdx.x >> 6;
    #pragma unroll
    for (int off = 32; off; off >>= 1) s += __shfl_down(s, off, 64);
    if (lane == 0) sm[w] = s;
    __syncthreads();
    if (threadIdx.x == 0) {
        float t = sm[0] + sm[1] + sm[2] + sm[3];
        out[b] = t / (float)N + addf[b] * fcw[H] + fcb[0];
    }
}

// ---------------------------------------------------------------- launch
extern "C" void kernel_launch(void* const* d_in, const int* in_sizes, int n_in,
                              void* d_out, int out_size, void* d_ws, size_t ws_size,
                              hipStream_t stream) {
    const float* x    = (const float*)d_in[0];
    const float* addf = (const float*)d_in[1];
    const int*   ei   = (const int*)d_in[2];
    const float* W1   = (const float*)d_in[3];
    const float* b1   = (const float*)d_in[4];
    const float* W2   = (const float*)d_in[5];
    const float* b2   = (const float*)d_in[6];
    const float* fcw  = (const float*)d_in[7];
    const float* fcb  = (const float*)d_in[8];
    float* out = (float*)d_out;

    const int B  = in_sizes[1];            // 8
    const int H  = in_sizes[4];            // 64
    const int IN = in_sizes[3] / H;        // 128
    const int E  = in_sizes[2] / 2;        // 320000
    const int N  = in_sizes[0] / (B * IN); // 20000
    const int* srcp = ei;
    const int* dstp = ei + E;

    const int M = B * N;                   // 160000 node-major rows

    size_t bufsz = (size_t)M * H;
    unsigned short* bufA = (unsigned short*)d_ws;      // hw1 [N][512] bf16
    unsigned short* bufB = bufA + bufsz;               // hw2 [N][512] bf16
    int*   cnt  = (int*)(bufB + bufsz);
    int*   rs   = cnt + N;
    int*   cur  = rs + N;
    int*   csrc = cur + N;
    float* cw   = (float*)(csrc + E);
    float* partial = (float*)(cw + E);

    const int nbE = (E + BLK - 1) / BLK;
    const int nodes2 = N / 2;              // gather blocks (2 nodes/block)

    // CSR build (discrete kernels; memset replaces the zero kernel)
    hipMemsetAsync(cnt, 0, (size_t)N * sizeof(int), stream);
    k_count<<<dim3(nbE), dim3(BLK), 0, stream>>>(dstp, cnt, E);
    k_scan_all<<<dim3(1), dim3(1024), 0, stream>>>(cnt, rs, cur, N);
    k_fill<<<dim3(nbE), dim3(BLK), 0, stream>>>(srcp, dstp, cnt, cur, csrc, cw, E);

    // layer 1: hw1 = bf16(x) @ bf16(W1) -> bufA (node-major)
    k_gemm_mfma<128><<<dim3((M + 127) / 128), dim3(BLK), 0, stream>>>(
        x, W1, bufA, M, N, B);

    // fused: agg1 = gather(hw1)+self+b1; hw2 = relu(agg1) @ W2 -> bufB
    k_gather_gemm<<<dim3(nodes2), dim3(BLK), 0, stream>>>(
        bufA, rs, cnt, csrc, cw, b1, W2, bufB, N);

    // fused final: gather(hw2)+self+b2, relu, mean-pool, FC dot -> partials
    k_gather_final<<<dim3(nodes2), dim3(BLK), 0, stream>>>(
        bufB, rs, cnt, csrc, cw, b2, fcw, partial, N);

    k_finish<<<dim3(B), dim3(BLK), 0, stream>>>(partial, nodes2, addf, fcw, fcb, out, N, H);
}